// Round 1
// baseline (830.766 us; speedup 1.0000x reference)
//
#include <hip/hip_runtime.h>
#include <hip/hip_bf16.h>

typedef unsigned short u16;
typedef __attribute__((ext_vector_type(8))) short shortx8;
typedef __attribute__((ext_vector_type(4))) float floatx4;

// ---------- helpers ----------
__device__ __forceinline__ float bf2f(u16 u) {
    union { unsigned int ui; float f; } x; x.ui = ((unsigned int)u) << 16; return x.f;
}
__device__ __forceinline__ u16 f2b(float f) {
    union { float f; unsigned int u; } x; x.f = f;
    unsigned int r = (x.u + 0x7fffu + ((x.u >> 16) & 1u)) >> 16;   // RNE
    return (u16)r;
}
__device__ __forceinline__ void glds16(const void* g, void* l) {
    __builtin_amdgcn_global_load_lds((const __attribute__((address_space(1))) void*)g,
                                     (__attribute__((address_space(3))) void*)l, 16, 0, 0);
}

// ---------- fp32 -> bf16 elementwise (encodings) ----------
__global__ __launch_bounds__(256) void cvt_bf16_kernel(const float* __restrict__ src,
                                                       u16* __restrict__ dst, int n) {
    int i = (blockIdx.x * 256 + threadIdx.x) * 4;
    if (i + 3 < n) {
        float4 v = *(const float4*)&src[i];
        ushort4 o; o.x = f2b(v.x); o.y = f2b(v.y); o.z = f2b(v.z); o.w = f2b(v.w);
        *(ushort4*)&dst[i] = o;
    }
}

// ---------- build Bsmall' [1024][512] bf16 (transposed [mu|sigma|fc1_b|fc2_b]) ----------
__global__ __launch_bounds__(256) void build_bsmall(const float* __restrict__ mu,
                                                    const float* __restrict__ sg,
                                                    const float* __restrict__ b1,
                                                    const float* __restrict__ b2,
                                                    u16* __restrict__ Bs) {
    int nrow = blockIdx.x;                 // 0..1023
    const float* src; int c;
    if (nrow < 256)      { src = mu; c = nrow; }
    else if (nrow < 512) { src = sg; c = nrow - 256; }
    else if (nrow < 768) { src = b1; c = nrow - 512; }
    else                 { src = b2; c = nrow - 768; }
    for (int k = threadIdx.x; k < 512; k += 256)
        Bs[(size_t)nrow * 512 + k] = f2b(src[(size_t)k * 256 + c]);
}

// ---------- fc_w fp32 [512][65536] -> bf16 transposed [65536][512] ----------
__global__ __launch_bounds__(256) void cvt_transpose(const float* __restrict__ W,
                                                     u16* __restrict__ Bt) {
    __shared__ float t[32][33];
    int n0 = blockIdx.x * 32, k0 = blockIdx.y * 32;
    int r  = threadIdx.x >> 3, c4 = (threadIdx.x & 7) * 4;
    float4 v = *(const float4*)&W[(size_t)(k0 + r) * 65536 + n0 + c4];
    t[r][c4] = v.x; t[r][c4 + 1] = v.y; t[r][c4 + 2] = v.z; t[r][c4 + 3] = v.w;
    __syncthreads();
    ushort4 o;
    o.x = f2b(t[c4 + 0][r]); o.y = f2b(t[c4 + 1][r]);
    o.z = f2b(t[c4 + 2][r]); o.w = f2b(t[c4 + 3][r]);
    *(ushort4*)&Bt[(size_t)(n0 + r) * 512 + k0 + c4] = o;
}

// ---------- slots = mu + exp(0.5*sig)*eps ----------
__global__ __launch_bounds__(256) void slots_kernel(const float* __restrict__ P,
                                                    const float* __restrict__ eps,
                                                    float* __restrict__ slots) {
    int t = blockIdx.x, d = threadIdx.x;
    float mu = P[(size_t)t * 1024 + d];
    float sg = expf(0.5f * P[(size_t)t * 1024 + 256 + d]);
    int b = t >> 6, n = t & 63;
    #pragma unroll
    for (int m = 0; m < 2; m++) {
        float e = eps[(size_t)(((b * 2 + m) * 64) + n) * 256 + d];
        slots[(size_t)t * 512 + m * 256 + d] = mu + sg * e;
    }
}

// ---------- MFMA GEMM: C[M][N] = A[M][K] * B'[N][K]^T  (bf16 in, fp32 acc) ----------
template<int OUT_BF16>
__global__ __launch_bounds__(256, 2) void gemm_bt(const u16* __restrict__ A,
                                                  const u16* __restrict__ B,
                                                  void* __restrict__ Cv,
                                                  int N, int K) {
    __shared__ __align__(16) u16 As[128 * 32];
    __shared__ __align__(16) u16 Bs[128 * 32];
    int tid = threadIdx.x;
    int wave = tid >> 6, lane = tid & 63;
    int m0 = blockIdx.x * 128, n0 = blockIdx.y * 128;
    int wm = wave >> 1, wn = wave & 1;

    floatx4 acc[4][4];
    #pragma unroll
    for (int r = 0; r < 4; r++)
        #pragma unroll
        for (int c = 0; c < 4; c++)
            #pragma unroll
            for (int q = 0; q < 4; q++) acc[r][c][q] = 0.f;

    int c0 = wave * 64;                       // chunk base for this wave
    int lrow = (c0 + lane) >> 2;              // 0..63
    int kof = (lane & 3) * 8;
    const u16* ga0 = A + (size_t)(m0 + lrow) * K + kof;
    const u16* ga1 = A + (size_t)(m0 + lrow + 64) * K + kof;
    const u16* gb0 = B + (size_t)(n0 + lrow) * K + kof;
    const u16* gb1 = B + (size_t)(n0 + lrow + 64) * K + kof;
    u16* la0 = As + c0 * 8;
    u16* la1 = As + (c0 + 256) * 8;
    u16* lb0 = Bs + c0 * 8;
    u16* lb1 = Bs + (c0 + 256) * 8;

    int fko = (lane >> 4) * 8;
    const u16* afp = As + (wm * 64 + (lane & 15)) * 32 + fko;
    const u16* bfp = Bs + (wn * 64 + (lane & 15)) * 32 + fko;

    for (int k0 = 0; k0 < K; k0 += 32) {
        glds16(ga0 + k0, la0);
        glds16(ga1 + k0, la1);
        glds16(gb0 + k0, lb0);
        glds16(gb1 + k0, lb1);
        __syncthreads();
        shortx8 af[4], bf[4];
        #pragma unroll
        for (int r = 0; r < 4; r++) af[r] = *(const shortx8*)(afp + r * 16 * 32);
        #pragma unroll
        for (int c = 0; c < 4; c++) bf[c] = *(const shortx8*)(bfp + c * 16 * 32);
        #pragma unroll
        for (int r = 0; r < 4; r++)
            #pragma unroll
            for (int c = 0; c < 4; c++)
                acc[r][c] = __builtin_amdgcn_mfma_f32_16x16x32_bf16(af[r], bf[c], acc[r][c], 0, 0, 0);
        __syncthreads();
    }

    int crow0 = m0 + wm * 64 + (lane >> 4) * 4;
    int ccol  = n0 + wn * 64 + (lane & 15);
    if (OUT_BF16) {
        u16* C = (u16*)Cv;
        #pragma unroll
        for (int r = 0; r < 4; r++)
            #pragma unroll
            for (int c = 0; c < 4; c++)
                #pragma unroll
                for (int q = 0; q < 4; q++)
                    C[(size_t)(crow0 + r * 16 + q) * N + ccol + c * 16] = f2b(acc[r][c][q]);
    } else {
        float* C = (float*)Cv;
        #pragma unroll
        for (int r = 0; r < 4; r++)
            #pragma unroll
            for (int c = 0; c < 4; c++)
                #pragma unroll
                for (int q = 0; q < 4; q++)
                    C[(size_t)(crow0 + r * 16 + q) * N + ccol + c * 16] = acc[r][c][q];
    }
}

// ---------- apply: y[t][m][h] = relu(sum_g s[t][m][g]*W[t][g][h] + bias[t][h]) ----------
__global__ __launch_bounds__(256) void apply_mlp(const u16* __restrict__ Wc,   // [NT][256][256] bf16
                                                 const float* __restrict__ P,  // [2048][1024]
                                                 const float* __restrict__ sin,// [2048][2][256]
                                                 float* __restrict__ yout,
                                                 int t0, int bias_col, int final_layout) {
    __shared__ float s[2][256];
    __shared__ float part[8][2][256];
    int tid = threadIdx.x;
    int tloc = blockIdx.x;
    int t = t0 + tloc;
    s[0][tid] = sin[(size_t)t * 512 + tid];
    s[1][tid] = sin[(size_t)t * 512 + 256 + tid];
    __syncthreads();

    int j = tid & 31, gg = tid >> 5;
    int jh = j * 8;
    float f0[8], f1[8];
    #pragma unroll
    for (int i = 0; i < 8; i++) { f0[i] = 0.f; f1[i] = 0.f; }
    const u16* wp = Wc + (size_t)tloc * 65536 + jh;
    for (int g = gg; g < 256; g += 8) {
        shortx8 wv = *(const shortx8*)(wp + (size_t)g * 256);
        float s0 = s[0][g], s1 = s[1][g];
        #pragma unroll
        for (int i = 0; i < 8; i++) {
            float w = bf2f((u16)wv[i]);
            f0[i] += s0 * w;
            f1[i] += s1 * w;
        }
    }
    float4* p0 = (float4*)&part[gg][0][jh];
    float4* p1 = (float4*)&part[gg][1][jh];
    float4 a0; a0.x = f0[0]; a0.y = f0[1]; a0.z = f0[2]; a0.w = f0[3];
    float4 a1; a1.x = f0[4]; a1.y = f0[5]; a1.z = f0[6]; a1.w = f0[7];
    float4 b0; b0.x = f1[0]; b0.y = f1[1]; b0.z = f1[2]; b0.w = f1[3];
    float4 b1; b1.x = f1[4]; b1.y = f1[5]; b1.z = f1[6]; b1.w = f1[7];
    p0[0] = a0; p0[1] = a1; p1[0] = b0; p1[1] = b1;
    __syncthreads();

    float bias = P[(size_t)t * 1024 + bias_col + tid];
    float y0 = bias, y1 = bias;
    #pragma unroll
    for (int p = 0; p < 8; p++) { y0 += part[p][0][tid]; y1 += part[p][1][tid]; }
    y0 = fmaxf(y0, 0.f); y1 = fmaxf(y1, 0.f);
    if (final_layout) {
        int b = t >> 6, n = t & 63;
        yout[(size_t)((b * 2 + 0) * 64 + n) * 256 + tid] = y0;
        yout[(size_t)((b * 2 + 1) * 64 + n) * 256 + tid] = y1;
    } else {
        yout[(size_t)t * 512 + tid] = y0;
        yout[(size_t)t * 512 + 256 + tid] = y1;
    }
}

// ---------- host ----------
extern "C" void kernel_launch(void* const* d_in, const int* in_sizes, int n_in,
                              void* d_out, int out_size, void* d_ws, size_t ws_size,
                              hipStream_t stream) {
    const float* enc = (const float*)d_in[0];
    const float* mu  = (const float*)d_in[1];
    const float* sg  = (const float*)d_in[2];
    const float* f1w = (const float*)d_in[3];
    const float* f1b = (const float*)d_in[4];
    const float* f2w = (const float*)d_in[5];
    const float* f2b = (const float*)d_in[6];
    const float* eps = (const float*)d_in[7];
    float* out = (float*)d_out;

    size_t off = 0;
    auto alloc = [&](size_t b) -> char* {
        char* p = (char*)d_ws + off; off += (b + 255) & ~(size_t)255; return p;
    };
    u16*   Eb    = (u16*)  alloc((size_t)2048 * 512 * 2);
    float* P     = (float*)alloc((size_t)2048 * 1024 * 4);
    float* slots = (float*)alloc((size_t)2048 * 512 * 4);
    float* h1    = (float*)alloc((size_t)2048 * 512 * 4);
    u16*   Bsm   = (u16*)  alloc((size_t)1024 * 512 * 2);
    u16*   Bt    = (u16*)  alloc((size_t)65536 * 512 * 2);
    size_t fixed = off;
    int NT = 2048;
    while (NT > 128 && fixed + (size_t)NT * 65536 * 2 > ws_size) NT >>= 1;
    u16* Wc = (u16*)alloc((size_t)NT * 65536 * 2);

    cvt_bf16_kernel<<<1024, 256, 0, stream>>>(enc, Eb, 2048 * 512);
    build_bsmall<<<1024, 256, 0, stream>>>(mu, sg, f1b, f2b, Bsm);
    gemm_bt<0><<<dim3(16, 8), 256, 0, stream>>>(Eb, Bsm, P, 1024, 512);
    slots_kernel<<<2048, 256, 0, stream>>>(P, eps, slots);

    for (int L = 0; L < 2; L++) {
        const float* fw = L ? f2w : f1w;
        cvt_transpose<<<dim3(2048, 16), 256, 0, stream>>>(fw, Bt);
        const float* sin_p = L ? h1 : slots;
        float* yo = L ? out : h1;
        for (int t0 = 0; t0 < 2048; t0 += NT) {
            gemm_bt<1><<<dim3(NT / 128, 512), 256, 0, stream>>>(Eb + (size_t)t0 * 512, Bt, Wc, 65536, 512);
            apply_mlp<<<NT, 256, 0, stream>>>(Wc, P, sin_p, yo, t0, 512 + L * 256, L);
        }
    }
}